// Round 11
// baseline (271.022 us; speedup 1.0000x reference)
//
#include <hip/hip_runtime.h>
#include <math.h>

// Problem constants (fixed by setup_inputs): B=4, L=4096, k=16, PE_DIM=64.
// d_out is a FLOAT32 buffer; harness bf16-quantizes both sides for compare.
namespace {
constexpr int BB  = 4;
constexpr int LL  = 4096;
constexpr int KK  = 16;
constexpr int NF  = 16;
constexpr int QPB = 8;                 // queries per block
constexpr int SPL = 32;                // splits per query (one half-wave)
constexpr int ITER = LL / (SPL * 2);   // 64 float4 iters (2 points each)
constexpr int ROWCAP = 200;            // survivor slots per query row
constexpr unsigned WMIN = 16, WMAX = 192;
constexpr unsigned FCAP = QPB * ROWCAP;   // 1600 fallback slots

constexpr size_t N_IDX    = (size_t)BB * LL * KK;                 // 262144
constexpr size_t OFF_RPE  = N_IDX;
constexpr size_t OFF_SELF = OFF_RPE + N_IDX * 64;                 // 17039360
constexpr size_t OFF_DIST = OFF_SELF + (size_t)BB * LL * 64;      // 18087936
constexpr size_t OFF_NPOS = OFF_DIST + N_IDX;                     // 18350080
}

__device__ __forceinline__ float bf16r(float x) {
  unsigned u = __float_as_uint(x);
  unsigned r = (u + 0x7FFFu + ((u >> 16) & 1u)) & 0xFFFF0000u;
  return __uint_as_float(r);
}

// XLA-exact squared distance: rn(dx*dx) + rn(dy*dy), no fma contraction
__device__ __forceinline__ float d2_of(float cx, float cy, float px, float py) {
  const float dx = cx - px, dy = cy - py;
  return __fadd_rn(__fmul_rn(dx, dx), __fmul_rn(dy, dy));
}

// seed tau: E[cnt]=64 under N(0,50^2); capped exp kills far-field blowup.
__device__ __forceinline__ float tau_seed(float px, float py) {
  const float r2 = __fadd_rn(__fmul_rn(px, px), __fmul_rn(py, py));
  return 19.53f * __expf(fminf(r2 * 2.0e-4f, 6.0f));
}

// ---- diagnostic: pure scan+count cost, counts -> d_ws (attribution only) ----
__global__ __launch_bounds__(256)
void scan_probe(const float* __restrict__ positions,
                unsigned int* __restrict__ ws)
{
  const int tid = threadIdx.x;
  const int b = blockIdx.x >> 9, brow = blockIdx.x & 511;
  const int q = tid >> 5, s = tid & 31;
  const int qrow = brow * QPB + q;
  const float2* p2 = (const float2*)positions + (size_t)b * LL;
  const float4* p4 = (const float4*)p2;
  const float2 P = p2[qrow];
  const float t1 = tau_seed(P.x, P.y);
  const float l0 = t1 * 0.015625f, l1 = t1 * 0.0625f, l2 = t1 * 0.25f,
              l3 = t1, l4 = t1 * 4.0f;
  unsigned c0 = 0, c1 = 0, c2 = 0, c3 = 0, c4 = 0;
  #pragma unroll 2
  for (int i = 0; i < ITER; ++i) {
    const int pi = i * SPL + s;
    const float4 v = p4[pi];
    const int ci0 = pi * 2, ci1 = ci0 + 1;
    {
      const float d2 = d2_of(v.x, v.y, P.x, P.y);
      const bool ok = (ci0 != qrow);
      c0 += ok && (d2 <= l0); c1 += ok && (d2 <= l1); c2 += ok && (d2 <= l2);
      c3 += ok && (d2 <= l3); c4 += ok && (d2 <= l4);
    }
    {
      const float d2 = d2_of(v.z, v.w, P.x, P.y);
      const bool ok = (ci1 != qrow);
      c0 += ok && (d2 <= l0); c1 += ok && (d2 <= l1); c2 += ok && (d2 <= l2);
      c3 += ok && (d2 <= l3); c4 += ok && (d2 <= l4);
    }
  }
  #pragma unroll
  for (int m = 16; m; m >>= 1) {
    c0 += __shfl_xor(c0, m, 32); c1 += __shfl_xor(c1, m, 32);
    c2 += __shfl_xor(c2, m, 32); c3 += __shfl_xor(c3, m, 32);
    c4 += __shfl_xor(c4, m, 32);
  }
  if (s == 0) {
    const size_t gq = (size_t)b * LL + qrow;
    ws[gq * 2]     = c3;
    ws[gq * 2 + 1] = c0 + c1 + c2 + c4;
  }
}

// ---- Kernel S: ballot-compacted scan + count-certified select ----
__global__ __launch_bounds__(256)
void sel4_kernel(const float* __restrict__ positions,
                 float* __restrict__ out)
{
  __shared__ unsigned long long surv[QPB][ROWCAP];   // 12.8 KB
  __shared__ unsigned int redc[QPB][5];
  __shared__ float        tbs[QPB];
  __shared__ unsigned int nq[QPB];
  __shared__ unsigned int flags;

  const int tid  = threadIdx.x;
  const int b    = blockIdx.x >> 9, brow = blockIdx.x & 511;
  const int q    = tid >> 5, s = tid & 31;
  const int qrow = brow * QPB + q;
  const bool hi_half = (tid & 32) != 0;
  const unsigned lowmask = (1u << s) - 1u;

  const float2* p2 = (const float2*)positions + (size_t)b * LL;
  const float4* p4 = (const float4*)p2;
  const float2  P  = p2[qrow];

  if (tid == 0) flags = 0u;

  const float t1 = tau_seed(P.x, P.y);
  const float l0 = t1 * 0.015625f, l1 = t1 * 0.0625f, l2 = t1 * 0.25f,
              l3 = t1, l4 = t1 * 4.0f;
  __syncthreads();                       // flags init visible

  // ---- scan: 5-level exact counts + ballot-append survivors at l3 ----
  unsigned c0 = 0, c1 = 0, c2 = 0, c3 = 0, c4 = 0;
  unsigned base = 0;
  #pragma unroll 2
  for (int i = 0; i < ITER; ++i) {
    const int pi = i * SPL + s;
    const float4 v = p4[pi];
    const int ci0 = pi * 2, ci1 = ci0 + 1;
    {
      const float d2 = d2_of(v.x, v.y, P.x, P.y);
      const bool ok = (ci0 != qrow);
      c0 += ok && (d2 <= l0); c1 += ok && (d2 <= l1); c2 += ok && (d2 <= l2);
      c3 += ok && (d2 <= l3); c4 += ok && (d2 <= l4);
      const bool pr = ok && (d2 <= l3);
      const unsigned long long bal = __ballot(pr);
      const unsigned mh = hi_half ? (unsigned)(bal >> 32) : (unsigned)bal;
      if (pr) {
        const unsigned slot = base + __popc(mh & lowmask);
        if (slot < (unsigned)ROWCAP)
          surv[q][slot] =
              ((unsigned long long)__float_as_uint(d2) << 32) | (unsigned)ci0;
      }
      base += __popc(mh);
    }
    {
      const float d2 = d2_of(v.z, v.w, P.x, P.y);
      const bool ok = (ci1 != qrow);
      c0 += ok && (d2 <= l0); c1 += ok && (d2 <= l1); c2 += ok && (d2 <= l2);
      c3 += ok && (d2 <= l3); c4 += ok && (d2 <= l4);
      const bool pr = ok && (d2 <= l3);
      const unsigned long long bal = __ballot(pr);
      const unsigned mh = hi_half ? (unsigned)(bal >> 32) : (unsigned)bal;
      if (pr) {
        const unsigned slot = base + __popc(mh & lowmask);
        if (slot < (unsigned)ROWCAP)
          surv[q][slot] =
              ((unsigned long long)__float_as_uint(d2) << 32) | (unsigned)ci1;
      }
      base += __popc(mh);
    }
  }

  // half-wave (width-32) reduce: all lanes end with totals
  #pragma unroll
  for (int m = 16; m; m >>= 1) {
    c0 += __shfl_xor(c0, m, 32); c1 += __shfl_xor(c1, m, 32);
    c2 += __shfl_xor(c2, m, 32); c3 += __shfl_xor(c3, m, 32);
    c4 += __shfl_xor(c4, m, 32);
  }

  // level select: prefer l3 (already stored), else smallest fitting
  int lev; float tr; unsigned n;
  if      (c3 >= WMIN && c3 <= WMAX) { lev = 3; tr = 0.0f; n = c3; }
  else if (c0 >= WMIN && c0 <= WMAX) { lev = 0; tr = l0;   n = c0; }
  else if (c1 >= WMIN && c1 <= WMAX) { lev = 1; tr = l1;   n = c1; }
  else if (c2 >= WMIN && c2 <= WMAX) { lev = 2; tr = l2;   n = c2; }
  else if (c4 >= WMIN && c4 <= WMAX) { lev = 4; tr = l4;   n = c4; }
  else                               { lev = -1; tr = -1.0f; n = 0; }

  // rescan-append at verified level (half-wave divergence is safe: ballot
  // masks inactive lanes to 0, base stays half-uniform)
  if (lev >= 0 && lev != 3) {
    base = 0;
    #pragma unroll 2
    for (int i = 0; i < ITER; ++i) {
      const int pi = i * SPL + s;
      const float4 v = p4[pi];
      const int ci0 = pi * 2, ci1 = ci0 + 1;
      {
        const float d2 = d2_of(v.x, v.y, P.x, P.y);
        const bool pr = (d2 <= tr) && (ci0 != qrow);
        const unsigned long long bal = __ballot(pr);
        const unsigned mh = hi_half ? (unsigned)(bal >> 32) : (unsigned)bal;
        if (pr) {
          const unsigned slot = base + __popc(mh & lowmask);
          if (slot < (unsigned)ROWCAP)
            surv[q][slot] =
                ((unsigned long long)__float_as_uint(d2) << 32) | (unsigned)ci0;
        }
        base += __popc(mh);
      }
      {
        const float d2 = d2_of(v.z, v.w, P.x, P.y);
        const bool pr = (d2 <= tr) && (ci1 != qrow);
        const unsigned long long bal = __ballot(pr);
        const unsigned mh = hi_half ? (unsigned)(bal >> 32) : (unsigned)bal;
        if (pr) {
          const unsigned slot = base + __popc(mh & lowmask);
          if (slot < (unsigned)ROWCAP)
            surv[q][slot] =
                ((unsigned long long)__float_as_uint(d2) << 32) | (unsigned)ci1;
        }
        base += __popc(mh);
      }
    }
  }

  if (s == 0) {
    if (lev < 0) atomicOr(&flags, 1u << q);
    nq[q] = n; tbs[q] = t1;
    redc[q][0] = c0; redc[q][1] = c1; redc[q][2] = c2;
    redc[q][3] = c3; redc[q][4] = c4;
  }
  __syncthreads();

  // ---- rank-select: 32 lanes/query, exact rank by counting ----
  const unsigned fl = flags;
  if (!((fl >> q) & 1u)) {
    const int nn = (int)nq[q];             // in [16,192], complete set
    const size_t g3 = (size_t)b * LL + qrow;
    for (int j = s; j < nn; j += 32) {
      const unsigned long long k = surv[q][j];
      int rank = 0;
      for (int j2 = 0; j2 < nn; ++j2) rank += (surv[q][j2] < k);
      if (rank < KK)
        out[g3 * KK + rank] = (float)(unsigned)(k & 0xFFFFFFFFu);
    }
  }

  // ---- fallback: block-parallel collect + rank (rare) ----
  unsigned fb = fl;
  while (fb) {
    const int fq = __ffs((int)fb) - 1; fb &= fb - 1u;
    __syncthreads();                       // prior surv readers done
    const int fqrow = brow * QPB + fq;
    const float2 FP = p2[fqrow];
    const float ft1 = tbs[fq];
    const unsigned f0 = redc[fq][0], f1 = redc[fq][1], f2 = redc[fq][2],
                   f3 = redc[fq][3], f4 = redc[fq][4];
    float ftau; unsigned fn;                // smallest level with count >= 16
    if      (f0 >= WMIN) { ftau = ft1 * 0.015625f; fn = f0; }
    else if (f1 >= WMIN) { ftau = ft1 * 0.0625f;   fn = f1; }
    else if (f2 >= WMIN) { ftau = ft1 * 0.25f;     fn = f2; }
    else if (f3 >= WMIN) { ftau = ft1;             fn = f3; }
    else                 { ftau = ft1 * 4.0f;      fn = f4; }
    unsigned long long* fsurv = &surv[0][0];       // 1600 slots
    if (fn <= FCAP) {
      if (tid < 64) {                      // wave-0 ballot collect
        unsigned fbase = 0;
        const unsigned long long lm = (1ull << tid) - 1ull;
        for (int i = 0; i < LL / 128; ++i) {
          const int pi = i * 64 + tid;
          const float4 v = p4[pi];
          const int ci0 = pi * 2, ci1 = ci0 + 1;
          {
            const float d2 = d2_of(v.x, v.y, FP.x, FP.y);
            const bool pr = (d2 <= ftau) && (ci0 != fqrow);
            const unsigned long long bal = __ballot(pr);
            if (pr) {
              const unsigned slot = fbase + (unsigned)__popcll(bal & lm);
              if (slot < FCAP)
                fsurv[slot] = ((unsigned long long)__float_as_uint(d2) << 32) |
                              (unsigned)ci0;
            }
            fbase += (unsigned)__popcll(bal);
          }
          {
            const float d2 = d2_of(v.z, v.w, FP.x, FP.y);
            const bool pr = (d2 <= ftau) && (ci1 != fqrow);
            const unsigned long long bal = __ballot(pr);
            if (pr) {
              const unsigned slot = fbase + (unsigned)__popcll(bal & lm);
              if (slot < FCAP)
                fsurv[slot] = ((unsigned long long)__float_as_uint(d2) << 32) |
                              (unsigned)ci1;
            }
            fbase += (unsigned)__popcll(bal);
          }
        }
      }
      __syncthreads();
      const size_t gf = (size_t)b * LL + fqrow;
      for (int j = tid; j < (int)fn; j += 256) {
        const unsigned long long k = fsurv[j];
        int rank = 0;
        for (int j2 = 0; j2 < (int)fn; ++j2) rank += (fsurv[j2] < k);
        if (rank < KK)
          out[gf * KK + rank] = (float)(unsigned)(k & 0xFFFFFFFFu);
      }
    } else {
      // last-resort exact bubble (R10-proven); probability ~0
      __syncthreads();
      if (tid < 16) {
        unsigned long long key[KK];
        #pragma unroll
        for (int j = 0; j < KK; ++j) key[j] = ~0ULL;
        unsigned dmax = 0xFFFFFFFFu;
        for (int i = 0; i < 256; ++i) {
          const int ci = tid + i * 16;
          const float d2 = d2_of(p2[ci].x, p2[ci].y, FP.x, FP.y);
          const unsigned d2b = __float_as_uint(d2);
          if (d2b < dmax && ci != fqrow) {
            unsigned long long kj =
                ((unsigned long long)d2b << 32) | (unsigned)ci;
            #pragma unroll
            for (int j = 0; j < KK; ++j) {
              const bool lt = kj < key[j];
              const unsigned long long nk = lt ? kj : key[j];
              const unsigned long long ok2 = lt ? key[j] : kj;
              key[j] = nk; kj = ok2;
            }
            dmax = (unsigned)(key[KK - 1] >> 32);
          }
        }
        #pragma unroll
        for (int j = 0; j < KK; ++j) fsurv[tid * KK + j] = key[j];
      }
      __syncthreads();
      if (tid == 0) {
        int h[16];
        #pragma unroll
        for (int j = 0; j < 16; ++j) h[j] = 0;
        const size_t gf = (size_t)b * LL + fqrow;
        #pragma unroll
        for (int r = 0; r < KK; ++r) {
          unsigned long long bk = ~0ULL; int bj = 0;
          #pragma unroll
          for (int j = 0; j < 16; ++j) {
            const unsigned long long v = (h[j] < KK) ? fsurv[j * KK + h[j]] : ~0ULL;
            const bool better = v < bk;
            bk = better ? v : bk;
            bj = better ? j : bj;
          }
          #pragma unroll
          for (int j = 0; j < 16; ++j) h[j] += (j == bj) ? 1 : 0;
          out[gf * KK + r] = (float)(unsigned)(bk & 0xFFFFFFFFu);
        }
      }
    }
  }
}

// ---- Kernel E: one thread per (query, neighbor); all other outputs ----
__global__ __launch_bounds__(256)
void emit_kernel(const float* __restrict__ positions,
                 float* __restrict__ out)
{
  const int gid = blockIdx.x * 256 + threadIdx.x;    // [0, 262144)
  const size_t g  = (size_t)gid;
  const size_t gq = g >> 4;
  const int b     = (int)(gq >> 12);
  const int qrow  = (int)(gq & 4095);

  const float2* p2 = (const float2*)positions + (size_t)b * LL;
  const int ci = (int)out[g];

  const float2 P = p2[qrow];
  const float2 c = p2[ci];
  const float dx = c.x - P.x;
  const float dy = c.y - P.y;
  const float d2 = __fadd_rn(__fmul_rn(dx, dx), __fmul_rn(dy, dy));

  out[OFF_DIST + g] = bf16r(sqrtf(__fadd_rn(d2, 1e-8f)));
  {
    float2* np_ = (float2*)(out + OFF_NPOS) + g;
    *np_ = make_float2(bf16r(c.x), bf16r(c.y));
  }

  const float SCALE = (float)(3.0 * sqrt(16.0 / M_PI));
  const float PI_F  = (float)M_PI;
  const float tx = dx / SCALE;
  const float ty = dy / SCALE;

  float sxv[NF], cxv[NF], syv[NF], cyv[NF];
  #pragma unroll
  for (int f = 0; f < NF; ++f) {
    const float fr = PI_F * (float)(1 << f);
    sincosf(__fmul_rn(tx, fr), &sxv[f], &cxv[f]);
    sincosf(__fmul_rn(ty, fr), &syv[f], &cyv[f]);
  }
  float4* rp = (float4*)(out + OFF_RPE + g * 64);
  #pragma unroll
  for (int w = 0; w < 4; ++w)
    rp[w]      = make_float4(bf16r(sxv[w*4]), bf16r(sxv[w*4+1]),
                             bf16r(sxv[w*4+2]), bf16r(sxv[w*4+3]));
  #pragma unroll
  for (int w = 0; w < 4; ++w)
    rp[4 + w]  = make_float4(bf16r(cxv[w*4]), bf16r(cxv[w*4+1]),
                             bf16r(cxv[w*4+2]), bf16r(cxv[w*4+3]));
  #pragma unroll
  for (int w = 0; w < 4; ++w)
    rp[8 + w]  = make_float4(bf16r(syv[w*4]), bf16r(syv[w*4+1]),
                             bf16r(syv[w*4+2]), bf16r(syv[w*4+3]));
  #pragma unroll
  for (int w = 0; w < 4; ++w)
    rp[12 + w] = make_float4(bf16r(cyv[w*4]), bf16r(cyv[w*4+1]),
                             bf16r(cyv[w*4+2]), bf16r(cyv[w*4+3]));

  {
    const float v = ((g >> 2) & 1) ? 1.0f : 0.0f;
    float4* sp = (float4*)(out + OFF_SELF) + g;
    *sp = make_float4(v, v, v, v);
  }
}

extern "C" void kernel_launch(void* const* d_in, const int* in_sizes, int n_in,
                              void* d_out, int out_size, void* d_ws, size_t ws_size,
                              hipStream_t stream) {
  const float* positions = (const float*)d_in[0];
  float* out = (float*)d_out;

  if (ws_size >= (size_t)BB * LL * 2 * sizeof(unsigned)) {   // attribution probe
    scan_probe<<<dim3(BB * (LL / QPB)), dim3(QPB * SPL), 0, stream>>>(
        positions, (unsigned*)d_ws);
  }
  sel4_kernel<<<dim3(BB * (LL / QPB)), dim3(QPB * SPL), 0, stream>>>(positions, out);
  emit_kernel<<<dim3((int)(N_IDX / 256)), dim3(256),    0, stream>>>(positions, out);
}

// Round 12
// 164.497 us; speedup vs baseline: 1.6476x; 1.6476x over previous
//
#include <hip/hip_runtime.h>
#include <math.h>

// Problem constants (fixed by setup_inputs): B=4, L=4096, k=16, PE_DIM=64.
// d_out is a FLOAT32 buffer; harness bf16-quantizes both sides for compare.
namespace {
constexpr int BB  = 4;
constexpr int LL  = 4096;
constexpr int KK  = 16;
constexpr int NF  = 16;
constexpr int QPB = 8;                 // queries per block
constexpr int SPL = 32;                // splits per query (one half-wave)
constexpr int ITER = LL / (SPL * 2);   // 64 float4 iters (2 points each)
constexpr int ROWCAP = 240;            // survivor slots per query row
constexpr unsigned WMIN = 16, WMAX = 240;
constexpr int NLEV = 8;                // tau ladder: t1 * 2^(m-4), m=0..7

constexpr size_t N_IDX    = (size_t)BB * LL * KK;                 // 262144
constexpr size_t OFF_RPE  = N_IDX;
constexpr size_t OFF_SELF = OFF_RPE + N_IDX * 64;                 // 17039360
constexpr size_t OFF_DIST = OFF_SELF + (size_t)BB * LL * 64;      // 18087936
constexpr size_t OFF_NPOS = OFF_DIST + N_IDX;                     // 18350080
}

__device__ __forceinline__ float bf16r(float x) {
  unsigned u = __float_as_uint(x);
  unsigned r = (u + 0x7FFFu + ((u >> 16) & 1u)) & 0xFFFF0000u;
  return __uint_as_float(r);
}

// XLA-exact squared distance: rn(dx*dx) + rn(dy*dy), no fma contraction
__device__ __forceinline__ float d2_of(float cx, float cy, float px, float py) {
  const float dx = cx - px, dy = cy - py;
  return __fadd_rn(__fmul_rn(dx, dx), __fmul_rn(dy, dy));
}

// ---- Kernel S: certified single-scan top-16 ----
// tau seed: E[cnt] = 64 under N(0,50^2): 64/(L/(2s^2)) = 78.125.
// 8-level x2 ladder certifies a level in [16,240] for any realizable
// geometry; bulk queries certify at the append level (no rescan).
__global__ __launch_bounds__(256)
void sel5_kernel(const float* __restrict__ positions,
                 float* __restrict__ out)
{
  __shared__ unsigned long long surv[QPB][ROWCAP];   // 15360 B
  __shared__ unsigned int nq[QPB];
  __shared__ unsigned int flags;

  const int tid  = threadIdx.x;
  const int b    = blockIdx.x >> 9, brow = blockIdx.x & 511;
  const int q    = tid >> 5, s = tid & 31;
  const int qrow = brow * QPB + q;
  const bool hi_half = (tid & 32) != 0;
  const unsigned lowmask = (1u << s) - 1u;

  const float2* p2 = (const float2*)positions + (size_t)b * LL;
  const float4* p4 = (const float4*)p2;
  const float2  P  = p2[qrow];

  if (tid == 0) flags = 0u;

  const float r2 = __fadd_rn(__fmul_rn(P.x, P.x), __fmul_rn(P.y, P.y));
  const float t1 = 78.125f * __expf(fminf(r2 * 2.0e-4f, 6.0f));
  float lv[NLEV];
  constexpr float LVC[NLEV] = {0.0625f, 0.125f, 0.25f, 0.5f,
                               1.0f, 2.0f, 4.0f, 8.0f};
  #pragma unroll
  for (int j = 0; j < NLEV; ++j) lv[j] = t1 * LVC[j];
  __syncthreads();                       // flags init visible

  // ---- scan: 8-level exact counts + ballot-append survivors at lv[4] ----
  unsigned cnt[NLEV] = {0, 0, 0, 0, 0, 0, 0, 0};
  unsigned base = 0;
  #pragma unroll 2
  for (int i = 0; i < ITER; ++i) {
    const int pi = i * SPL + s;
    const float4 v = p4[pi];
    const int ci0 = pi * 2, ci1 = ci0 + 1;
    {
      const float d2 = d2_of(v.x, v.y, P.x, P.y);
      const bool ok = (ci0 != qrow);
      #pragma unroll
      for (int j = 0; j < NLEV; ++j) cnt[j] += ok && (d2 <= lv[j]);
      const bool pr = ok && (d2 <= lv[4]);
      const unsigned long long bal = __ballot(pr);
      const unsigned mh = hi_half ? (unsigned)(bal >> 32) : (unsigned)bal;
      if (pr) {
        const unsigned slot = base + __popc(mh & lowmask);
        if (slot < (unsigned)ROWCAP)
          surv[q][slot] =
              ((unsigned long long)__float_as_uint(d2) << 32) | (unsigned)ci0;
      }
      base += __popc(mh);
    }
    {
      const float d2 = d2_of(v.z, v.w, P.x, P.y);
      const bool ok = (ci1 != qrow);
      #pragma unroll
      for (int j = 0; j < NLEV; ++j) cnt[j] += ok && (d2 <= lv[j]);
      const bool pr = ok && (d2 <= lv[4]);
      const unsigned long long bal = __ballot(pr);
      const unsigned mh = hi_half ? (unsigned)(bal >> 32) : (unsigned)bal;
      if (pr) {
        const unsigned slot = base + __popc(mh & lowmask);
        if (slot < (unsigned)ROWCAP)
          surv[q][slot] =
              ((unsigned long long)__float_as_uint(d2) << 32) | (unsigned)ci1;
      }
      base += __popc(mh);
    }
  }

  // half-wave (width-32) reduce: every lane gets exact totals
  #pragma unroll
  for (int j = 0; j < NLEV; ++j) {
    #pragma unroll
    for (int m = 16; m; m >>= 1) cnt[j] += __shfl_xor(cnt[j], m, 32);
  }

  // level choice: prefer append level (no rescan); else smallest certified
  const bool use4 = (cnt[4] >= WMIN && cnt[4] <= WMAX);
  int m = -1;
  #pragma unroll
  for (int j = 0; j < NLEV; ++j) if (m < 0 && cnt[j] >= WMIN) m = j;
  unsigned n = 0; float tr = 0.0f;
  #pragma unroll
  for (int j = 0; j < NLEV; ++j) if (j == m) { n = cnt[j]; tr = lv[j]; }
  const bool lastresort = (m < 0) || (!use4 && n > WMAX);

  if (use4) {
    n = cnt[4];
  } else if (!lastresort) {
    // rescan-append at certified level (rare: ~capped far-field queries)
    base = 0;
    #pragma unroll 2
    for (int i = 0; i < ITER; ++i) {
      const int pi = i * SPL + s;
      const float4 v = p4[pi];
      const int ci0 = pi * 2, ci1 = ci0 + 1;
      {
        const float d2 = d2_of(v.x, v.y, P.x, P.y);
        const bool pr = (d2 <= tr) && (ci0 != qrow);
        const unsigned long long bal = __ballot(pr);
        const unsigned mh = hi_half ? (unsigned)(bal >> 32) : (unsigned)bal;
        if (pr) {
          const unsigned slot = base + __popc(mh & lowmask);
          if (slot < (unsigned)ROWCAP)
            surv[q][slot] =
                ((unsigned long long)__float_as_uint(d2) << 32) | (unsigned)ci0;
        }
        base += __popc(mh);
      }
      {
        const float d2 = d2_of(v.z, v.w, P.x, P.y);
        const bool pr = (d2 <= tr) && (ci1 != qrow);
        const unsigned long long bal = __ballot(pr);
        const unsigned mh = hi_half ? (unsigned)(bal >> 32) : (unsigned)bal;
        if (pr) {
          const unsigned slot = base + __popc(mh & lowmask);
          if (slot < (unsigned)ROWCAP)
            surv[q][slot] =
                ((unsigned long long)__float_as_uint(d2) << 32) | (unsigned)ci1;
        }
        base += __popc(mh);
      }
    }
  }

  if (s == 0) {
    nq[q] = n;
    if (lastresort) atomicOr(&flags, 1u << q);
  }
  __syncthreads();

  // ---- rank-select: 32 lanes/query, exact rank by counting ----
  const unsigned fl = flags;
  if (!((fl >> q) & 1u)) {
    const int nn = (int)nq[q];             // in [16,240], complete set
    const size_t g3 = (size_t)b * LL + qrow;
    for (int j = s; j < nn; j += 32) {
      const unsigned long long k = surv[q][j];
      int rank = 0;
      for (int j2 = 0; j2 < nn; ++j2) rank += (surv[q][j2] < k);
      if (rank < KK)
        out[g3 * KK + rank] = (float)(unsigned)(k & 0xFFFFFFFFu);
    }
  }

  // ---- last-resort exact path (probability ~0; kept for certainty) ----
  unsigned fb = fl;
  while (fb) {
    const int fq = __ffs((int)fb) - 1; fb &= fb - 1u;
    __syncthreads();                       // surv readers done before reuse
    const int fqrow = brow * QPB + fq;
    const float2 FP = p2[fqrow];
    unsigned long long* scratch = &surv[0][0];   // 512 u64 = 4 KB
    if (tid < 32) {                        // 32-lane bubble over 128 cands each
      unsigned long long key[KK];
      #pragma unroll
      for (int j = 0; j < KK; ++j) key[j] = ~0ULL;
      unsigned dmax = 0xFFFFFFFFu;
      for (int i = 0; i < LL / 32; ++i) {
        const int ci = tid + i * 32;
        const float d2 = d2_of(p2[ci].x, p2[ci].y, FP.x, FP.y);
        const unsigned d2b = __float_as_uint(d2);
        if (d2b < dmax && ci != fqrow) {
          unsigned long long kj =
              ((unsigned long long)d2b << 32) | (unsigned)ci;
          #pragma unroll
          for (int j = 0; j < KK; ++j) {
            const bool lt = kj < key[j];
            const unsigned long long nk = lt ? kj : key[j];
            const unsigned long long ok2 = lt ? key[j] : kj;
            key[j] = nk; kj = ok2;
          }
          dmax = (unsigned)(key[KK - 1] >> 32);
        }
      }
      #pragma unroll
      for (int j = 0; j < KK; ++j) scratch[tid * KK + j] = key[j];
    }
    __syncthreads();
    if (tid == 0) {                        // 32-way merge of sorted 16-lists
      int h[32];
      #pragma unroll
      for (int j = 0; j < 32; ++j) h[j] = 0;
      const size_t gf = (size_t)b * LL + fqrow;
      #pragma unroll
      for (int r = 0; r < KK; ++r) {
        unsigned long long bk = ~0ULL; int bj = 0;
        #pragma unroll
        for (int j = 0; j < 32; ++j) {
          const unsigned long long v = (h[j] < KK) ? scratch[j * KK + h[j]] : ~0ULL;
          const bool better = v < bk;
          bk = better ? v : bk;
          bj = better ? j : bj;
        }
        #pragma unroll
        for (int j = 0; j < 32; ++j) h[j] += (j == bj) ? 1 : 0;
        out[gf * KK + r] = (float)(unsigned)(bk & 0xFFFFFFFFu);
      }
    }
  }
}

// ---- Kernel E: one thread per (query, neighbor); all other outputs ----
__global__ __launch_bounds__(256)
void emit_kernel(const float* __restrict__ positions,
                 float* __restrict__ out)
{
  const int gid = blockIdx.x * 256 + threadIdx.x;    // [0, 262144)
  const size_t g  = (size_t)gid;
  const size_t gq = g >> 4;
  const int b     = (int)(gq >> 12);
  const int qrow  = (int)(gq & 4095);

  const float2* p2 = (const float2*)positions + (size_t)b * LL;
  const int ci = (int)out[g];

  const float2 P = p2[qrow];
  const float2 c = p2[ci];
  const float dx = c.x - P.x;
  const float dy = c.y - P.y;
  const float d2 = __fadd_rn(__fmul_rn(dx, dx), __fmul_rn(dy, dy));

  out[OFF_DIST + g] = bf16r(sqrtf(__fadd_rn(d2, 1e-8f)));
  {
    float2* np_ = (float2*)(out + OFF_NPOS) + g;
    *np_ = make_float2(bf16r(c.x), bf16r(c.y));
  }

  const float SCALE = (float)(3.0 * sqrt(16.0 / M_PI));
  const float PI_F  = (float)M_PI;
  const float tx = dx / SCALE;
  const float ty = dy / SCALE;

  float sxv[NF], cxv[NF], syv[NF], cyv[NF];
  #pragma unroll
  for (int f = 0; f < NF; ++f) {
    const float fr = PI_F * (float)(1 << f);
    sincosf(__fmul_rn(tx, fr), &sxv[f], &cxv[f]);
    sincosf(__fmul_rn(ty, fr), &syv[f], &cyv[f]);
  }
  float4* rp = (float4*)(out + OFF_RPE + g * 64);
  #pragma unroll
  for (int w = 0; w < 4; ++w)
    rp[w]      = make_float4(bf16r(sxv[w*4]), bf16r(sxv[w*4+1]),
                             bf16r(sxv[w*4+2]), bf16r(sxv[w*4+3]));
  #pragma unroll
  for (int w = 0; w < 4; ++w)
    rp[4 + w]  = make_float4(bf16r(cxv[w*4]), bf16r(cxv[w*4+1]),
                             bf16r(cxv[w*4+2]), bf16r(cxv[w*4+3]));
  #pragma unroll
  for (int w = 0; w < 4; ++w)
    rp[8 + w]  = make_float4(bf16r(syv[w*4]), bf16r(syv[w*4+1]),
                             bf16r(syv[w*4+2]), bf16r(syv[w*4+3]));
  #pragma unroll
  for (int w = 0; w < 4; ++w)
    rp[12 + w] = make_float4(bf16r(cyv[w*4]), bf16r(cyv[w*4+1]),
                             bf16r(cyv[w*4+2]), bf16r(cyv[w*4+3]));

  {
    const float v = ((g >> 2) & 1) ? 1.0f : 0.0f;
    float4* sp = (float4*)(out + OFF_SELF) + g;
    *sp = make_float4(v, v, v, v);
  }
}

extern "C" void kernel_launch(void* const* d_in, const int* in_sizes, int n_in,
                              void* d_out, int out_size, void* d_ws, size_t ws_size,
                              hipStream_t stream) {
  const float* positions = (const float*)d_in[0];
  float* out = (float*)d_out;

  // 4 batches x 512 blocks (8 queries each) = 2048 blocks
  sel5_kernel<<<dim3(BB * (LL / QPB)), dim3(QPB * SPL), 0, stream>>>(positions, out);
  emit_kernel<<<dim3((int)(N_IDX / 256)), dim3(256),    0, stream>>>(positions, out);
}

// Round 13
// 163.989 us; speedup vs baseline: 1.6527x; 1.0031x over previous
//
#include <hip/hip_runtime.h>
#include <math.h>

// Problem constants (fixed by setup_inputs): B=4, L=4096, k=16, PE_DIM=64.
// d_out is a FLOAT32 buffer; harness bf16-quantizes both sides for compare.
namespace {
constexpr int BB  = 4;
constexpr int LL  = 4096;
constexpr int KK  = 16;
constexpr int NF  = 16;
constexpr int QPB = 8;                 // queries per block
constexpr int SPL = 32;                // splits per query (one half-wave)
constexpr int ITER = LL / (SPL * 2);   // 64 float4 iters (2 points each)
constexpr int ROWCAP = 256;            // survivor slots per query row
constexpr unsigned WMIN = 16;

constexpr size_t N_IDX    = (size_t)BB * LL * KK;                 // 262144
constexpr size_t OFF_RPE  = N_IDX;
constexpr size_t OFF_SELF = OFF_RPE + N_IDX * 64;                 // 17039360
constexpr size_t OFF_DIST = OFF_SELF + (size_t)BB * LL * 64;      // 18087936
constexpr size_t OFF_NPOS = OFF_DIST + N_IDX;                     // 18350080
}

__device__ __forceinline__ float bf16r(float x) {
  unsigned u = __float_as_uint(x);
  unsigned r = (u + 0x7FFFu + ((u >> 16) & 1u)) & 0xFFFF0000u;
  return __uint_as_float(r);
}

// XLA-exact squared distance: rn(dx*dx) + rn(dy*dy), no fma contraction
__device__ __forceinline__ float d2_of(float cx, float cy, float px, float py) {
  const float dx = cx - px, dy = cy - py;
  return __fadd_rn(__fmul_rn(dx, dx), __fmul_rn(dy, dy));
}

// ---- Kernel S: single-count scan; in-window -> rank-select,
//      miss -> half-wave exhaustive bubble + shfl-min merge (exact). ----
__global__ __launch_bounds__(256)
void sel6_kernel(const float* __restrict__ positions,
                 float* __restrict__ out)
{
  __shared__ unsigned long long surv[QPB][ROWCAP];   // 16 KB

  const int tid  = threadIdx.x;
  const int b    = blockIdx.x >> 9, brow = blockIdx.x & 511;
  const int q    = tid >> 5, s = tid & 31;
  const int qrow = brow * QPB + q;
  const bool hi_half = (tid & 32) != 0;
  const unsigned lowmask = (1u << s) - 1u;

  const float2* p2 = (const float2*)positions + (size_t)b * LL;
  const float4* p4 = (const float4*)p2;
  const float2  P  = p2[qrow];

  // tau: E[cnt]=64 under N(0,50^2); cap at e^4 (disk radius 65) so the
  // count is monotone-decreasing in |p| -> no mid-field overflow. Heuristic
  // only: the exact count 'base' certifies, misses go to the exact branch.
  const float r2 = __fadd_rn(__fmul_rn(P.x, P.x), __fmul_rn(P.y, P.y));
  const float tau = 78.125f * __expf(fminf(r2 * 2.0e-4f, 4.0f));

  // ---- scan: ballot-append survivors at tau; base = exact count ----
  unsigned base = 0;
  #pragma unroll 2
  for (int i = 0; i < ITER; ++i) {
    const int pi = i * SPL + s;
    const float4 v = p4[pi];
    const int ci0 = pi * 2, ci1 = ci0 + 1;
    {
      const float d2 = d2_of(v.x, v.y, P.x, P.y);
      const bool pr = (d2 <= tau) && (ci0 != qrow);
      const unsigned long long bal = __ballot(pr);
      const unsigned mh = hi_half ? (unsigned)(bal >> 32) : (unsigned)bal;
      if (pr) {
        const unsigned slot = base + __popc(mh & lowmask);
        if (slot < (unsigned)ROWCAP)
          surv[q][slot] =
              ((unsigned long long)__float_as_uint(d2) << 32) | (unsigned)ci0;
      }
      base += __popc(mh);
    }
    {
      const float d2 = d2_of(v.z, v.w, P.x, P.y);
      const bool pr = (d2 <= tau) && (ci1 != qrow);
      const unsigned long long bal = __ballot(pr);
      const unsigned mh = hi_half ? (unsigned)(bal >> 32) : (unsigned)bal;
      if (pr) {
        const unsigned slot = base + __popc(mh & lowmask);
        if (slot < (unsigned)ROWCAP)
          surv[q][slot] =
              ((unsigned long long)__float_as_uint(d2) << 32) | (unsigned)ci1;
      }
      base += __popc(mh);
    }
  }
  __syncthreads();   // surv visible across the half-wave's lanes

  const size_t g3 = (size_t)b * LL + qrow;

  if (base >= WMIN && base <= (unsigned)ROWCAP) {
    // ---- rank-select: 32 lanes/query, exact rank by counting ----
    const int nn = (int)base;              // complete survivor set
    for (int j = s; j < nn; j += 32) {
      const unsigned long long k = surv[q][j];
      int rank = 0;
      for (int j2 = 0; j2 < nn; ++j2) rank += (surv[q][j2] < k);
      if (rank < KK)
        out[g3 * KK + rank] = (float)(unsigned)(k & 0xFFFFFFFFu);
    }
  } else {
    // ---- exact path (rare: ~1e-3 of queries): 32-lane bubble over all
    //      4096 candidates + 16-round shfl-min merge, no LDS, no barrier ----
    unsigned long long key[KK];
    #pragma unroll
    for (int j = 0; j < KK; ++j) key[j] = ~0ULL;
    unsigned dmax = 0xFFFFFFFFu;
    for (int i = 0; i < LL / 32; ++i) {    // 128 candidates per lane
      const int ci = s + i * 32;
      const float2 c = p2[ci];
      const float d2 = d2_of(c.x, c.y, P.x, P.y);
      const unsigned d2b = __float_as_uint(d2);
      if (d2b < dmax && ci != qrow) {
        unsigned long long kj =
            ((unsigned long long)d2b << 32) | (unsigned)ci;
        #pragma unroll
        for (int j = 0; j < KK; ++j) {     // predicated bubble, static idx
          const bool lt = kj < key[j];
          const unsigned long long nk = lt ? kj : key[j];
          const unsigned long long ok = lt ? key[j] : kj;
          key[j] = nk; kj = ok;
        }
        dmax = (unsigned)(key[KK - 1] >> 32);
      }
    }
    // merge 32 sorted lists: 16 rounds of width-32 min + winner-pop
    #pragma unroll
    for (int r = 0; r < KK; ++r) {
      unsigned long long m = key[0];
      #pragma unroll
      for (int off = 16; off; off >>= 1) {
        const unsigned long long o = __shfl_xor(m, off, 32);
        m = (o < m) ? o : m;
      }
      if (key[0] == m) {                   // unique winner (keys distinct)
        out[g3 * KK + r] = (float)(unsigned)(m & 0xFFFFFFFFu);
        #pragma unroll
        for (int j = 0; j < KK - 1; ++j) key[j] = key[j + 1];
        key[KK - 1] = ~0ULL;
      }
    }
  }
}

// ---- Kernel E: one thread per (query, neighbor); all other outputs ----
__global__ __launch_bounds__(256)
void emit_kernel(const float* __restrict__ positions,
                 float* __restrict__ out)
{
  const int gid = blockIdx.x * 256 + threadIdx.x;    // [0, 262144)
  const size_t g  = (size_t)gid;
  const size_t gq = g >> 4;
  const int b     = (int)(gq >> 12);
  const int qrow  = (int)(gq & 4095);

  const float2* p2 = (const float2*)positions + (size_t)b * LL;
  const int ci = (int)out[g];

  const float2 P = p2[qrow];
  const float2 c = p2[ci];
  const float dx = c.x - P.x;
  const float dy = c.y - P.y;
  const float d2 = __fadd_rn(__fmul_rn(dx, dx), __fmul_rn(dy, dy));

  out[OFF_DIST + g] = bf16r(sqrtf(__fadd_rn(d2, 1e-8f)));
  {
    float2* np_ = (float2*)(out + OFF_NPOS) + g;
    *np_ = make_float2(bf16r(c.x), bf16r(c.y));
  }

  const float SCALE = (float)(3.0 * sqrt(16.0 / M_PI));
  const float PI_F  = (float)M_PI;
  const float tx = dx / SCALE;
  const float ty = dy / SCALE;

  float sxv[NF], cxv[NF], syv[NF], cyv[NF];
  #pragma unroll
  for (int f = 0; f < NF; ++f) {
    const float fr = PI_F * (float)(1 << f);
    sincosf(__fmul_rn(tx, fr), &sxv[f], &cxv[f]);
    sincosf(__fmul_rn(ty, fr), &syv[f], &cyv[f]);
  }
  float4* rp = (float4*)(out + OFF_RPE + g * 64);
  #pragma unroll
  for (int w = 0; w < 4; ++w)
    rp[w]      = make_float4(bf16r(sxv[w*4]), bf16r(sxv[w*4+1]),
                             bf16r(sxv[w*4+2]), bf16r(sxv[w*4+3]));
  #pragma unroll
  for (int w = 0; w < 4; ++w)
    rp[4 + w]  = make_float4(bf16r(cxv[w*4]), bf16r(cxv[w*4+1]),
                             bf16r(cxv[w*4+2]), bf16r(cxv[w*4+3]));
  #pragma unroll
  for (int w = 0; w < 4; ++w)
    rp[8 + w]  = make_float4(bf16r(syv[w*4]), bf16r(syv[w*4+1]),
                             bf16r(syv[w*4+2]), bf16r(syv[w*4+3]));
  #pragma unroll
  for (int w = 0; w < 4; ++w)
    rp[12 + w] = make_float4(bf16r(cyv[w*4]), bf16r(cyv[w*4+1]),
                             bf16r(cyv[w*4+2]), bf16r(cyv[w*4+3]));

  {
    const float v = ((g >> 2) & 1) ? 1.0f : 0.0f;
    float4* sp = (float4*)(out + OFF_SELF) + g;
    *sp = make_float4(v, v, v, v);
  }
}

extern "C" void kernel_launch(void* const* d_in, const int* in_sizes, int n_in,
                              void* d_out, int out_size, void* d_ws, size_t ws_size,
                              hipStream_t stream) {
  const float* positions = (const float*)d_in[0];
  float* out = (float*)d_out;

  // 4 batches x 512 blocks (8 queries each) = 2048 blocks
  sel6_kernel<<<dim3(BB * (LL / QPB)), dim3(QPB * SPL), 0, stream>>>(positions, out);
  emit_kernel<<<dim3((int)(N_IDX / 256)), dim3(256),    0, stream>>>(positions, out);
}

// Round 14
// 162.782 us; speedup vs baseline: 1.6649x; 1.0074x over previous
//
#include <hip/hip_runtime.h>
#include <math.h>

// Problem constants (fixed by setup_inputs): B=4, L=4096, k=16, PE_DIM=64.
// d_out is a FLOAT32 buffer; harness bf16-quantizes both sides for compare.
namespace {
constexpr int BB  = 4;
constexpr int LL  = 4096;
constexpr int KK  = 16;
constexpr int NF  = 16;
constexpr int QPB = 8;                 // queries per block
constexpr int SPL = 32;                // splits per query (one half-wave)
constexpr int ITER = LL / (SPL * 2);   // 64 float4 iters (2 points each)
constexpr int ROWCAP = 256;            // survivor slots per query row
constexpr unsigned WMIN = 17;          // window lower bound (incl. self)

constexpr size_t N_IDX    = (size_t)BB * LL * KK;                 // 262144
constexpr size_t OFF_RPE  = N_IDX;
constexpr size_t OFF_SELF = OFF_RPE + N_IDX * 64;                 // 17039360
constexpr size_t OFF_DIST = OFF_SELF + (size_t)BB * LL * 64;      // 18087936
constexpr size_t OFF_NPOS = OFF_DIST + N_IDX;                     // 18350080
}

__device__ __forceinline__ float bf16r(float x) {
  unsigned u = __float_as_uint(x);
  unsigned r = (u + 0x7FFFu + ((u >> 16) & 1u)) & 0xFFFF0000u;
  return __uint_as_float(r);
}

// XLA-exact squared distance: rn(dx*dx) + rn(dy*dy), no fma contraction
__device__ __forceinline__ float d2_of(float cx, float cy, float px, float py) {
  const float dx = cx - px, dy = cy - py;
  return __fadd_rn(__fmul_rn(dx, dx), __fmul_rn(dy, dy));
}

// pass 1: per-lane exact count of d2<=tau over this lane's 128 points
// (self included: d2=0 always passes -> no per-point identity mask)
__device__ __forceinline__ unsigned count_pass(const float4* __restrict__ p4,
                                               float2 P, float tau, int s) {
  unsigned c = 0;
  #pragma unroll 4
  for (int i = 0; i < ITER; ++i) {
    const float4 v = p4[i * SPL + s];
    c += (d2_of(v.x, v.y, P.x, P.y) <= tau);
    c += (d2_of(v.z, v.w, P.x, P.y) <= tau);
  }
  return c;
}

// half-wave inclusive prefix -> private base + uniform total
__device__ __forceinline__ void prefix32(unsigned c, int s,
                                         unsigned& base, unsigned& total) {
  unsigned inc = c;
  #pragma unroll
  for (int off = 1; off < 32; off <<= 1) {
    const unsigned y = __shfl_up(inc, off, 32);
    if (s >= off) inc += y;
  }
  base  = inc - c;
  total = __shfl(inc, 31, 32);
}

// pass 2: lane-private appends at precomputed base (no ballot/atomics).
// Bounds guaranteed: loc ends at base+c <= total <= ROWCAP (same tau, same ops).
__device__ __forceinline__ void append_pass(const float4* __restrict__ p4,
                                            float2 P, float tau, int s,
                                            unsigned long long* __restrict__ row,
                                            unsigned base) {
  unsigned loc = base;
  #pragma unroll 2
  for (int i = 0; i < ITER; ++i) {
    const int pi = i * SPL + s;
    const float4 v = p4[pi];
    const float da = d2_of(v.x, v.y, P.x, P.y);
    const float db = d2_of(v.z, v.w, P.x, P.y);
    if (da <= tau)
      row[loc++] = ((unsigned long long)__float_as_uint(da) << 32) |
                   (unsigned)(pi * 2);
    if (db <= tau)
      row[loc++] = ((unsigned long long)__float_as_uint(db) << 32) |
                   (unsigned)(pi * 2 + 1);
  }
}

// ---- Kernel S: count -> prefix -> append -> rank-select, per half-wave,
//      barrier-free. Miss: one certified tau-rescale retry, then exact bubble.
__global__ __launch_bounds__(256)
void sel7_kernel(const float* __restrict__ positions,
                 float* __restrict__ out)
{
  __shared__ unsigned long long surv[QPB][ROWCAP];   // 16 KB

  const int tid  = threadIdx.x;
  const int b    = blockIdx.x >> 9, brow = blockIdx.x & 511;
  const int q    = tid >> 5, s = tid & 31;
  const int qrow = brow * QPB + q;

  const float2* p2 = (const float2*)positions + (size_t)b * LL;
  const float4* p4 = (const float4*)p2;
  const float2  P  = p2[qrow];
  unsigned long long* row = &surv[q][0];
  const size_t g3 = (size_t)b * LL + qrow;

  // tau: E[cnt]=64 under N(0,50^2), capped at e^4 (count monotone in |p|).
  // Heuristic only — the exact count certifies; misses retry/fall back.
  const float r2 = __fadd_rn(__fmul_rn(P.x, P.x), __fmul_rn(P.y, P.y));
  float tau = 78.125f * __expf(fminf(r2 * 2.0e-4f, 4.0f));

  unsigned c = count_pass(p4, P, tau, s);
  unsigned base, total;
  prefix32(c, s, base, total);
  bool ok = (total >= WMIN && total <= (unsigned)ROWCAP);

  if (!ok) {                      // one certified rescale retry (rare)
    const float tau2 = tau * fminf(48.0f / fmaxf((float)total, 1.0f), 64.0f);
    c = count_pass(p4, P, tau2, s);
    unsigned b2, t2;
    prefix32(c, s, b2, t2);
    if (t2 >= WMIN && t2 <= (unsigned)ROWCAP) {
      tau = tau2; base = b2; total = t2; ok = true;
    }
  }

  if (ok) {
    append_pass(p4, P, tau, s, row, base);
    // rank-select: 32 lanes/query; self key = qrow (d2 bits = 0)
    const unsigned long long selfkey = (unsigned long long)(unsigned)qrow;
    const int nn = (int)total;
    for (int j = s; j < nn; j += 32) {
      const unsigned long long k = row[j];
      if (k != selfkey) {
        int rank = 0;
        for (int j2 = 0; j2 < nn; ++j2) rank += (row[j2] < k);
        rank -= (selfkey < k) ? 1 : 0;       // exact: drop self's contribution
        if (rank < KK)
          out[g3 * KK + rank] = (float)(unsigned)(k & 0xFFFFFFFFu);
      }
    }
  } else {
    // ---- exact path (probability ~0): 32-lane bubble + shfl-min merge ----
    unsigned long long key[KK];
    #pragma unroll
    for (int j = 0; j < KK; ++j) key[j] = ~0ULL;
    unsigned dmax = 0xFFFFFFFFu;
    for (int i = 0; i < LL / 32; ++i) {      // 128 candidates per lane
      const int ci = s + i * 32;
      const float2 cc = p2[ci];
      const float d2 = d2_of(cc.x, cc.y, P.x, P.y);
      const unsigned d2b = __float_as_uint(d2);
      if (d2b < dmax && ci != qrow) {
        unsigned long long kj =
            ((unsigned long long)d2b << 32) | (unsigned)ci;
        #pragma unroll
        for (int j = 0; j < KK; ++j) {       // predicated bubble, static idx
          const bool lt = kj < key[j];
          const unsigned long long nk = lt ? kj : key[j];
          const unsigned long long ok2 = lt ? key[j] : kj;
          key[j] = nk; kj = ok2;
        }
        dmax = (unsigned)(key[KK - 1] >> 32);
      }
    }
    #pragma unroll
    for (int r = 0; r < KK; ++r) {           // 16 rounds width-32 min + pop
      unsigned long long m = key[0];
      #pragma unroll
      for (int off = 16; off; off >>= 1) {
        const unsigned long long o = __shfl_xor(m, off, 32);
        m = (o < m) ? o : m;
      }
      if (key[0] == m) {                     // unique winner (keys distinct)
        out[g3 * KK + r] = (float)(unsigned)(m & 0xFFFFFFFFu);
        #pragma unroll
        for (int j = 0; j < KK - 1; ++j) key[j] = key[j + 1];
        key[KK - 1] = ~0ULL;
      }
    }
  }
}

// ---- Kernel E: one thread per (query, neighbor); all other outputs ----
__global__ __launch_bounds__(256)
void emit_kernel(const float* __restrict__ positions,
                 float* __restrict__ out)
{
  const int gid = blockIdx.x * 256 + threadIdx.x;    // [0, 262144)
  const size_t g  = (size_t)gid;
  const size_t gq = g >> 4;
  const int b     = (int)(gq >> 12);
  const int qrow  = (int)(gq & 4095);

  const float2* p2 = (const float2*)positions + (size_t)b * LL;
  const int ci = (int)out[g];

  const float2 P = p2[qrow];
  const float2 c = p2[ci];
  const float dx = c.x - P.x;
  const float dy = c.y - P.y;
  const float d2 = __fadd_rn(__fmul_rn(dx, dx), __fmul_rn(dy, dy));

  out[OFF_DIST + g] = bf16r(sqrtf(__fadd_rn(d2, 1e-8f)));
  {
    float2* np_ = (float2*)(out + OFF_NPOS) + g;
    *np_ = make_float2(bf16r(c.x), bf16r(c.y));
  }

  const float SCALE = (float)(3.0 * sqrt(16.0 / M_PI));
  const float PI_F  = (float)M_PI;
  const float tx = dx / SCALE;
  const float ty = dy / SCALE;

  float sxv[NF], cxv[NF], syv[NF], cyv[NF];
  #pragma unroll
  for (int f = 0; f < NF; ++f) {
    const float fr = PI_F * (float)(1 << f);
    sincosf(__fmul_rn(tx, fr), &sxv[f], &cxv[f]);
    sincosf(__fmul_rn(ty, fr), &syv[f], &cyv[f]);
  }
  float4* rp = (float4*)(out + OFF_RPE + g * 64);
  #pragma unroll
  for (int w = 0; w < 4; ++w)
    rp[w]      = make_float4(bf16r(sxv[w*4]), bf16r(sxv[w*4+1]),
                             bf16r(sxv[w*4+2]), bf16r(sxv[w*4+3]));
  #pragma unroll
  for (int w = 0; w < 4; ++w)
    rp[4 + w]  = make_float4(bf16r(cxv[w*4]), bf16r(cxv[w*4+1]),
                             bf16r(cxv[w*4+2]), bf16r(cxv[w*4+3]));
  #pragma unroll
  for (int w = 0; w < 4; ++w)
    rp[8 + w]  = make_float4(bf16r(syv[w*4]), bf16r(syv[w*4+1]),
                             bf16r(syv[w*4+2]), bf16r(syv[w*4+3]));
  #pragma unroll
  for (int w = 0; w < 4; ++w)
    rp[12 + w] = make_float4(bf16r(cyv[w*4]), bf16r(cyv[w*4+1]),
                             bf16r(cyv[w*4+2]), bf16r(cyv[w*4+3]));

  {
    const float v = ((g >> 2) & 1) ? 1.0f : 0.0f;
    float4* sp = (float4*)(out + OFF_SELF) + g;
    *sp = make_float4(v, v, v, v);
  }
}

extern "C" void kernel_launch(void* const* d_in, const int* in_sizes, int n_in,
                              void* d_out, int out_size, void* d_ws, size_t ws_size,
                              hipStream_t stream) {
  const float* positions = (const float*)d_in[0];
  float* out = (float*)d_out;

  // 4 batches x 512 blocks (8 queries each) = 2048 blocks
  sel7_kernel<<<dim3(BB * (LL / QPB)), dim3(QPB * SPL), 0, stream>>>(positions, out);
  emit_kernel<<<dim3((int)(N_IDX / 256)), dim3(256),    0, stream>>>(positions, out);
}